// Round 2
// baseline (789.366 us; speedup 1.0000x reference)
//
#include <hip/hip_runtime.h>

// SparseGCNPredicator on MI355X — ALL float tensors are FLOAT32 (reference
// declares jnp.float32; round-1 forensics: bf16 misread -> inf-inf=NaN ->
// fmaxf(NaN,0)=0 -> exact-zero output, matching the observed bit-exact
// stub error. No bf16 floor in threshold => no bf16 inputs.)
// Inputs: node_feats f32 [N,128], adj i32 [2,E], graph_idx i32 [N],
// is_training i32 (ignored), W1/b1/W2/b2/Wfc/bfc/Wout/bout f32.
// Output: f32 [G,1] (out_size = 1024).

typedef unsigned short ushort_t;
typedef unsigned int   uint_t;

__device__ __forceinline__ float bf2f(uint_t u) { return __uint_as_float(u << 16); }
__device__ __forceinline__ ushort_t f2bf(float f) {
  uint_t x = __float_as_uint(f);
  x = x + 0x7fffu + ((x >> 16) & 1u);   // round-to-nearest-even
  return (ushort_t)(x >> 16);
}

// ---------------- CSR build ----------------

__global__ __launch_bounds__(256) void k_deg(const int* __restrict__ dst, int* __restrict__ deg, int E) {
  int e = blockIdx.x * 256 + threadIdx.x;
  if (e < E) atomicAdd(&deg[dst[e]], 1);
}

__global__ __launch_bounds__(256) void k_scanA(const int* __restrict__ deg, int* __restrict__ bsum, int n) {
  __shared__ int s[256];
  int t = threadIdx.x;
  int base = blockIdx.x * 1024 + t * 4;
  int sum = 0;
#pragma unroll
  for (int j = 0; j < 4; j++) { int i = base + j; if (i < n) sum += deg[i]; }
  s[t] = sum; __syncthreads();
  for (int off = 128; off > 0; off >>= 1) { if (t < off) s[t] += s[t + off]; __syncthreads(); }
  if (t == 0) bsum[blockIdx.x] = s[0];
}

// exclusive scan of <=256 block sums, single block of 256 threads
__global__ __launch_bounds__(256) void k_scanB(const int* __restrict__ bsum, int* __restrict__ bbase, int nb) {
  __shared__ int s[256];
  int t = threadIdx.x;
  s[t] = (t < nb) ? bsum[t] : 0;
  __syncthreads();
  for (int off = 1; off < 256; off <<= 1) {
    int a = s[t];
    int add = (t >= off) ? s[t - off] : 0;
    __syncthreads();
    s[t] = a + add;
    __syncthreads();
  }
  if (t < nb) bbase[t] = (t > 0) ? s[t - 1] : 0;
}

__global__ __launch_bounds__(256) void k_scanC(const int* __restrict__ deg, const int* __restrict__ bbase,
                                               int* __restrict__ offs, int n) {
  __shared__ int s[256];
  int t = threadIdx.x;
  int base = blockIdx.x * 1024 + t * 4;
  int v[4]; int sum = 0;
#pragma unroll
  for (int j = 0; j < 4; j++) { int i = base + j; v[j] = (i < n) ? deg[i] : 0; sum += v[j]; }
  s[t] = sum; __syncthreads();
  for (int off = 1; off < 256; off <<= 1) {
    int a = s[t];
    int add = (t >= off) ? s[t - off] : 0;
    __syncthreads();
    s[t] = a + add;
    __syncthreads();
  }
  int excl = bbase[blockIdx.x] + ((t > 0) ? s[t - 1] : 0);
#pragma unroll
  for (int j = 0; j < 4; j++) { int i = base + j; if (i < n) offs[i] = excl; excl += v[j]; }
}

__global__ __launch_bounds__(256) void k_norm(const int* __restrict__ deg, float* __restrict__ nrm, int n) {
  int i = blockIdx.x * 256 + threadIdx.x;
  if (i < n) {
    int d = deg[i];
    nrm[i] = (d > 0) ? rsqrtf((float)d) : 0.f;
  }
}

__global__ __launch_bounds__(256) void k_bucket(const int* __restrict__ src, const int* __restrict__ dst,
                                                const int* __restrict__ offs, int* __restrict__ fill,
                                                int* __restrict__ esrc, int E) {
  int e = blockIdx.x * 256 + threadIdx.x;
  if (e >= E) return;
  int d = dst[e];
  int p = offs[d] + atomicAdd(&fill[d], 1);
  esrc[p] = src[e];
}

// ---------------- GEMM: Y[r] = (X[r] @ W + b) * norm[r] ----------------
// 32 rows per 256-thread block; each thread computes a 4x4 micro-tile.
// W staged through LDS in two 64-row halves (32 KB) + 16 KB X tile = 48 KB.
// BF16IN selects the input activation dtype (layer 2 reads bf16 h1).
template <bool BF16IN>
__global__ __launch_bounds__(256) void k_gemm(const void* __restrict__ Xv, const float* __restrict__ W,
                                              const float* __restrict__ bias, const float* __restrict__ nrm,
                                              float* __restrict__ Y, int nrows) {
  __shared__ float Ws[64 * 128];
  __shared__ float Xs[32 * 128];
  int tid = threadIdx.x;
  int r0 = blockIdx.x * 32;
  if (BF16IN) {
    const uint_t* Xp = (const uint_t*)Xv;  // 2 bf16 per uint
#pragma unroll
    for (int i = 0; i < 8; i++) {
      int idx = tid + 256 * i;             // pair index 0..2047
      int r = idx >> 6;                    // 0..31
      int cp = idx & 63;                   // pair column 0..63
      int gr = r0 + r;
      uint_t u = (gr < nrows) ? Xp[(size_t)gr * 64 + cp] : 0u;
      Xs[r * 128 + 2 * cp]     = bf2f(u & 0xffffu);
      Xs[r * 128 + 2 * cp + 1] = bf2f(u >> 16);
    }
  } else {
    const float4* Xp = (const float4*)Xv;  // 32 floats per row -> 32 float4
#pragma unroll
    for (int i = 0; i < 4; i++) {
      int idx = tid + 256 * i;             // float4 index 0..1023
      int r = idx >> 5;                    // 0..31
      int c4 = idx & 31;                   // float4 column 0..31
      int gr = r0 + r;
      float4 u = (gr < nrows) ? Xp[(size_t)gr * 32 + c4] : make_float4(0.f, 0.f, 0.f, 0.f);
      ((float4*)Xs)[r * 32 + c4] = u;
    }
  }
  int rq = tid >> 5;   // 0..7 -> rows rq*4..rq*4+3
  int cq = tid & 31;   // col quad
  float acc[4][4] = {{0.f}};
  const float4* Ws4 = (const float4*)Ws;
  for (int half = 0; half < 2; half++) {
    __syncthreads();   // protect Ws re-load (and Xs on first pass)
    {
      const float4* Wp = (const float4*)W + half * 2048;  // 64 rows x 32 float4
#pragma unroll
      for (int i = 0; i < 8; i++) {
        int idx = tid + 256 * i;           // 0..2047
        ((float4*)Ws)[idx] = Wp[idx];
      }
    }
    __syncthreads();
#pragma unroll 8
    for (int k = 0; k < 64; k++) {
      float4 wv = Ws4[k * 32 + cq];
      int kk = half * 64 + k;
#pragma unroll
      for (int j = 0; j < 4; j++) {
        float xv = Xs[(rq * 4 + j) * 128 + kk];
        acc[j][0] += xv * wv.x; acc[j][1] += xv * wv.y;
        acc[j][2] += xv * wv.z; acc[j][3] += xv * wv.w;
      }
    }
  }
  float bv[4];
#pragma unroll
  for (int j = 0; j < 4; j++) bv[j] = bias[cq * 4 + j];
#pragma unroll
  for (int j = 0; j < 4; j++) {
    int gr = r0 + rq * 4 + j;
    if (gr < nrows) {
      float nv = nrm[gr];
      float4 o;
      o.x = (acc[j][0] + bv[0]) * nv; o.y = (acc[j][1] + bv[1]) * nv;
      o.z = (acc[j][2] + bv[2]) * nv; o.w = (acc[j][3] + bv[3]) * nv;
      ((float4*)Y)[(size_t)gr * 32 + cq] = o;
    }
  }
}

// ---------------- Aggregation: out[i] = relu(norm[i] * sum_{e in CSR[i]} hn[src_e]) ----------------
// One 128-thread block per node; channel-per-thread, coalesced 512B row gathers.
__global__ __launch_bounds__(128) void k_agg_relu_bf16(const float* __restrict__ hn, const int* __restrict__ offs,
                                                       const int* __restrict__ deg, const float* __restrict__ nrm,
                                                       const int* __restrict__ esrc, ushort_t* __restrict__ out) {
  int i = blockIdx.x;
  int c = threadIdx.x;
  int o = offs[i], d = deg[i];
  float s = 0.f;
  for (int e = 0; e < d; e++) {
    int si = esrc[o + e];
    s += hn[(size_t)si * 128 + c];
  }
  float v = fmaxf(s * nrm[i], 0.f);
  out[(size_t)i * 128 + c] = f2bf(v);
}

// layer-2 aggregation with pooling fused (atomic f32 add into per-graph sums)
__global__ __launch_bounds__(128) void k_agg_relu_pool(const float* __restrict__ hn, const int* __restrict__ offs,
                                                       const int* __restrict__ deg, const float* __restrict__ nrm,
                                                       const int* __restrict__ esrc, const int* __restrict__ gidx,
                                                       float* __restrict__ pool) {
  int i = blockIdx.x;
  int c = threadIdx.x;
  int o = offs[i], d = deg[i];
  float s = 0.f;
  for (int e = 0; e < d; e++) s += hn[(size_t)esrc[o + e] * 128 + c];
  float v = fmaxf(s * nrm[i], 0.f);
  atomicAdd(&pool[(size_t)gidx[i] * 128 + c], v);
}

__global__ __launch_bounds__(256) void k_cnt(const int* __restrict__ gidx, int* __restrict__ cnt, int n) {
  int i = blockIdx.x * 256 + threadIdx.x;
  if (i < n) atomicAdd(&cnt[gidx[i]], 1);
}

// ---------------- Head: mean -> FC(relu) -> dot(Wout) + bout ----------------
__global__ __launch_bounds__(128) void k_head(const float* __restrict__ pool, const int* __restrict__ cnt,
                                              const float* __restrict__ Wfc, const float* __restrict__ bfc,
                                              const float* __restrict__ Wout, const float* __restrict__ bout,
                                              float* __restrict__ out) {
  __shared__ float pv[128];
  __shared__ float red[128];
  int g = blockIdx.x, t = threadIdx.x;
  float c = fmaxf((float)cnt[g], 1.f);
  pv[t] = pool[(size_t)g * 128 + t] / c;
  __syncthreads();
  float acc = bfc[t];
#pragma unroll 8
  for (int k = 0; k < 128; k++) acc += pv[k] * Wfc[k * 128 + t];
  acc = fmaxf(acc, 0.f);
  red[t] = acc * Wout[t];
  __syncthreads();
  for (int o = 64; o > 0; o >>= 1) { if (t < o) red[t] += red[t + o]; __syncthreads(); }
  if (t == 0) out[g] = red[0] + bout[0];
}

// ---------------- launch ----------------

extern "C" void kernel_launch(void* const* d_in, const int* in_sizes, int n_in,
                              void* d_out, int out_size, void* d_ws, size_t ws_size,
                              hipStream_t stream) {
  const float* X    = (const float*)d_in[0];
  const int*   adj  = (const int*)d_in[1];
  const int*   gidx = (const int*)d_in[2];
  // d_in[3] = is_training (ignored; dropout rate is 0)
  const float* W1   = (const float*)d_in[4];
  const float* b1   = (const float*)d_in[5];
  const float* W2   = (const float*)d_in[6];
  const float* b2   = (const float*)d_in[7];
  const float* Wfc  = (const float*)d_in[8];
  const float* bfc  = (const float*)d_in[9];
  const float* Wout = (const float*)d_in[10];
  const float* bout = (const float*)d_in[11];
  (void)n_in; (void)ws_size;

  const int N = in_sizes[2];        // 100000
  const int E = in_sizes[1] / 2;    // 1600000
  const int G = out_size;           // 1024 (OUT=1)
  const int* srcv = adj;
  const int* dstv = adj + E;

  char* w = (char*)d_ws;
  size_t off = 0;
  auto alloc = [&](size_t bytes) -> void* {
    void* p = (void*)(w + off);
    off += (bytes + 255) & ~(size_t)255;
    return p;
  };
  float*    bufA = (float*)alloc((size_t)N * 128 * sizeof(float));       // hn (gemm out), reused both layers
  ushort_t* bufB = (ushort_t*)alloc((size_t)N * 128 * sizeof(ushort_t)); // layer-1 activations (bf16)
  float*    pool = (float*)alloc((size_t)G * 128 * sizeof(float));
  float*    nrm  = (float*)alloc((size_t)N * sizeof(float));
  int*      deg  = (int*)alloc((size_t)N * sizeof(int));
  int*      offs = (int*)alloc((size_t)N * sizeof(int));
  int*      fill = (int*)alloc((size_t)N * sizeof(int));
  int*      esrc = (int*)alloc((size_t)E * sizeof(int));
  int*      cnt  = (int*)alloc((size_t)G * sizeof(int));
  const int nb = (N + 1023) / 1024;   // 98 (<=256 required by k_scanB)
  int*      bsum  = (int*)alloc((size_t)nb * sizeof(int));
  int*      bbase = (int*)alloc((size_t)nb * sizeof(int));

  hipMemsetAsync(deg,  0, (size_t)N * sizeof(int), stream);
  hipMemsetAsync(fill, 0, (size_t)N * sizeof(int), stream);
  hipMemsetAsync(pool, 0, (size_t)G * 128 * sizeof(float), stream);
  hipMemsetAsync(cnt,  0, (size_t)G * sizeof(int), stream);

  // CSR build (dst-major)
  k_deg<<<(E + 255) / 256, 256, 0, stream>>>(dstv, deg, E);
  k_scanA<<<nb, 256, 0, stream>>>(deg, bsum, N);
  k_scanB<<<1, 256, 0, stream>>>(bsum, bbase, nb);
  k_scanC<<<nb, 256, 0, stream>>>(deg, bbase, offs, N);
  k_norm<<<(N + 255) / 256, 256, 0, stream>>>(deg, nrm, N);
  k_bucket<<<(E + 255) / 256, 256, 0, stream>>>(srcv, dstv, offs, fill, esrc, E);

  // layer 1
  k_gemm<false><<<(N + 31) / 32, 256, 0, stream>>>((const void*)X, W1, b1, nrm, bufA, N);
  k_agg_relu_bf16<<<N, 128, 0, stream>>>(bufA, offs, deg, nrm, esrc, bufB);
  // layer 2 (+ fused pooling)
  k_gemm<true><<<(N + 31) / 32, 256, 0, stream>>>((const void*)bufB, W2, b2, nrm, bufA, N);
  k_agg_relu_pool<<<N, 128, 0, stream>>>(bufA, offs, deg, nrm, esrc, gidx, pool);
  k_cnt<<<(N + 255) / 256, 256, 0, stream>>>(gidx, cnt, N);
  // head
  k_head<<<G, 128, 0, stream>>>(pool, cnt, Wfc, bfc, Wout, bout, (float*)d_out);
}

// Round 3
// 618.745 us; speedup vs baseline: 1.2758x; 1.2758x over previous
//
#include <hip/hip_runtime.h>

// SparseGCNPredicator on MI355X — all float tensors are f32.
// R3: aggregation overhaul — hn stored bf16 (half gather bytes, 2x L2 hit),
// wave-per-node with 4B/lane loads, edge loop unrolled x4 with independent
// accumulators (4 gathers in flight per wave).

typedef unsigned short ushort_t;
typedef unsigned int   uint_t;

__device__ __forceinline__ float bf2f(uint_t u) { return __uint_as_float(u << 16); }
__device__ __forceinline__ ushort_t f2bf(float f) {
  uint_t x = __float_as_uint(f);
  x = x + 0x7fffu + ((x >> 16) & 1u);   // round-to-nearest-even
  return (ushort_t)(x >> 16);
}

// ---------------- CSR build ----------------

__global__ __launch_bounds__(256) void k_deg(const int* __restrict__ dst, int* __restrict__ deg, int E) {
  int e = blockIdx.x * 256 + threadIdx.x;
  if (e < E) atomicAdd(&deg[dst[e]], 1);
}

__global__ __launch_bounds__(256) void k_scanA(const int* __restrict__ deg, int* __restrict__ bsum, int n) {
  __shared__ int s[256];
  int t = threadIdx.x;
  int base = blockIdx.x * 1024 + t * 4;
  int sum = 0;
#pragma unroll
  for (int j = 0; j < 4; j++) { int i = base + j; if (i < n) sum += deg[i]; }
  s[t] = sum; __syncthreads();
  for (int off = 128; off > 0; off >>= 1) { if (t < off) s[t] += s[t + off]; __syncthreads(); }
  if (t == 0) bsum[blockIdx.x] = s[0];
}

// exclusive scan of <=256 block sums, single block of 256 threads
__global__ __launch_bounds__(256) void k_scanB(const int* __restrict__ bsum, int* __restrict__ bbase, int nb) {
  __shared__ int s[256];
  int t = threadIdx.x;
  s[t] = (t < nb) ? bsum[t] : 0;
  __syncthreads();
  for (int off = 1; off < 256; off <<= 1) {
    int a = s[t];
    int add = (t >= off) ? s[t - off] : 0;
    __syncthreads();
    s[t] = a + add;
    __syncthreads();
  }
  if (t < nb) bbase[t] = (t > 0) ? s[t - 1] : 0;
}

__global__ __launch_bounds__(256) void k_scanC(const int* __restrict__ deg, const int* __restrict__ bbase,
                                               int* __restrict__ offs, int n) {
  __shared__ int s[256];
  int t = threadIdx.x;
  int base = blockIdx.x * 1024 + t * 4;
  int v[4]; int sum = 0;
#pragma unroll
  for (int j = 0; j < 4; j++) { int i = base + j; v[j] = (i < n) ? deg[i] : 0; sum += v[j]; }
  s[t] = sum; __syncthreads();
  for (int off = 1; off < 256; off <<= 1) {
    int a = s[t];
    int add = (t >= off) ? s[t - off] : 0;
    __syncthreads();
    s[t] = a + add;
    __syncthreads();
  }
  int excl = bbase[blockIdx.x] + ((t > 0) ? s[t - 1] : 0);
#pragma unroll
  for (int j = 0; j < 4; j++) { int i = base + j; if (i < n) offs[i] = excl; excl += v[j]; }
}

__global__ __launch_bounds__(256) void k_norm(const int* __restrict__ deg, float* __restrict__ nrm, int n) {
  int i = blockIdx.x * 256 + threadIdx.x;
  if (i < n) {
    int d = deg[i];
    nrm[i] = (d > 0) ? rsqrtf((float)d) : 0.f;
  }
}

__global__ __launch_bounds__(256) void k_bucket(const int* __restrict__ src, const int* __restrict__ dst,
                                                const int* __restrict__ offs, int* __restrict__ fill,
                                                int* __restrict__ esrc, int E) {
  int e = blockIdx.x * 256 + threadIdx.x;
  if (e >= E) return;
  int d = dst[e];
  int p = offs[d] + atomicAdd(&fill[d], 1);
  esrc[p] = src[e];
}

// ---------------- GEMM: Yb[r] = bf16( (X[r] @ W + b) * norm[r] ) ----------------
// 32 rows per 256-thread block; each thread computes a 4x4 micro-tile.
// W staged through LDS in two 64-row halves (32 KB) + 16 KB X tile = 48 KB.
// BF16IN selects the input activation dtype (layer 2 reads bf16 h1).
// Output is packed bf16 (uint2 per 4 channels) — feeds the bf16 gather.
template <bool BF16IN>
__global__ __launch_bounds__(256) void k_gemm(const void* __restrict__ Xv, const float* __restrict__ W,
                                              const float* __restrict__ bias, const float* __restrict__ nrm,
                                              uint_t* __restrict__ Yb, int nrows) {
  __shared__ float Ws[64 * 128];
  __shared__ float Xs[32 * 128];
  int tid = threadIdx.x;
  int r0 = blockIdx.x * 32;
  if (BF16IN) {
    const uint_t* Xp = (const uint_t*)Xv;  // 2 bf16 per uint
#pragma unroll
    for (int i = 0; i < 8; i++) {
      int idx = tid + 256 * i;             // pair index 0..2047
      int r = idx >> 6;                    // 0..31
      int cp = idx & 63;                   // pair column 0..63
      int gr = r0 + r;
      uint_t u = (gr < nrows) ? Xp[(size_t)gr * 64 + cp] : 0u;
      Xs[r * 128 + 2 * cp]     = bf2f(u & 0xffffu);
      Xs[r * 128 + 2 * cp + 1] = bf2f(u >> 16);
    }
  } else {
    const float4* Xp = (const float4*)Xv;  // 32 floats per row -> 32 float4
#pragma unroll
    for (int i = 0; i < 4; i++) {
      int idx = tid + 256 * i;             // float4 index 0..1023
      int r = idx >> 5;                    // 0..31
      int c4 = idx & 31;                   // float4 column 0..31
      int gr = r0 + r;
      float4 u = (gr < nrows) ? Xp[(size_t)gr * 32 + c4] : make_float4(0.f, 0.f, 0.f, 0.f);
      ((float4*)Xs)[r * 32 + c4] = u;
    }
  }
  int rq = tid >> 5;   // 0..7 -> rows rq*4..rq*4+3
  int cq = tid & 31;   // col quad (channels 4*cq..4*cq+3)
  float acc[4][4] = {{0.f}};
  const float4* Ws4 = (const float4*)Ws;
  for (int half = 0; half < 2; half++) {
    __syncthreads();   // protect Ws re-load (and Xs on first pass)
    {
      const float4* Wp = (const float4*)W + half * 2048;  // 64 rows x 32 float4
#pragma unroll
      for (int i = 0; i < 8; i++) {
        int idx = tid + 256 * i;           // 0..2047
        ((float4*)Ws)[idx] = Wp[idx];
      }
    }
    __syncthreads();
#pragma unroll 8
    for (int k = 0; k < 64; k++) {
      float4 wv = Ws4[k * 32 + cq];
      int kk = half * 64 + k;
#pragma unroll
      for (int j = 0; j < 4; j++) {
        float xv = Xs[(rq * 4 + j) * 128 + kk];
        acc[j][0] += xv * wv.x; acc[j][1] += xv * wv.y;
        acc[j][2] += xv * wv.z; acc[j][3] += xv * wv.w;
      }
    }
  }
  float bv[4];
#pragma unroll
  for (int j = 0; j < 4; j++) bv[j] = bias[cq * 4 + j];
#pragma unroll
  for (int j = 0; j < 4; j++) {
    int gr = r0 + rq * 4 + j;
    if (gr < nrows) {
      float nv = nrm[gr];
      float o0 = (acc[j][0] + bv[0]) * nv, o1 = (acc[j][1] + bv[1]) * nv;
      float o2 = (acc[j][2] + bv[2]) * nv, o3 = (acc[j][3] + bv[3]) * nv;
      uint2 pk;
      pk.x = (uint_t)f2bf(o0) | ((uint_t)f2bf(o1) << 16);
      pk.y = (uint_t)f2bf(o2) | ((uint_t)f2bf(o3) << 16);
      ((uint2*)Yb)[(size_t)gr * 32 + cq] = pk;   // row = 64 uints = 128 bf16
    }
  }
}

// ---------------- Aggregation: relu(norm[i] * sum_{e in CSR[i]} hn_bf16[src_e]) ----------------
// One 64-lane wave per node (4 nodes / 256-thread block). Lane owns channels
// {2*lane, 2*lane+1} via one uint (bf16 pair) load -> 256 B/row/wave.
// Edge loop unrolled x4 with independent accumulators: 4 gathers in flight.
template <bool POOL>
__global__ __launch_bounds__(256) void k_agg(const uint_t* __restrict__ hn, const int* __restrict__ offs,
                                             const int* __restrict__ deg, const float* __restrict__ nrm,
                                             const int* __restrict__ esrc, const int* __restrict__ gidx,
                                             uint_t* __restrict__ outb, float* __restrict__ pool, int N) {
  int wave = threadIdx.x >> 6;
  int lane = threadIdx.x & 63;
  int i = blockIdx.x * 4 + wave;
  if (i >= N) return;
  int o = offs[i], d = deg[i];
  const uint_t* base = hn + lane;
  float s0 = 0.f, s1 = 0.f, t0 = 0.f, t1 = 0.f;
  float u0 = 0.f, u1 = 0.f, v0 = 0.f, v1 = 0.f;
  int e = o, end = o + d;
  for (; e + 4 <= end; e += 4) {
    int i0 = esrc[e], i1 = esrc[e + 1], i2 = esrc[e + 2], i3 = esrc[e + 3];
    uint_t a = base[(size_t)i0 * 64];
    uint_t b = base[(size_t)i1 * 64];
    uint_t c = base[(size_t)i2 * 64];
    uint_t q = base[(size_t)i3 * 64];
    s0 += bf2f(a & 0xffffu); s1 += bf2f(a >> 16);
    t0 += bf2f(b & 0xffffu); t1 += bf2f(b >> 16);
    u0 += bf2f(c & 0xffffu); u1 += bf2f(c >> 16);
    v0 += bf2f(q & 0xffffu); v1 += bf2f(q >> 16);
  }
  for (; e < end; e++) {
    uint_t a = base[(size_t)esrc[e] * 64];
    s0 += bf2f(a & 0xffffu); s1 += bf2f(a >> 16);
  }
  float nv = nrm[i];
  float r0 = fmaxf((s0 + t0 + u0 + v0) * nv, 0.f);
  float r1 = fmaxf((s1 + t1 + u1 + v1) * nv, 0.f);
  if (POOL) {
    float* p = pool + (size_t)gidx[i] * 128 + 2 * lane;
    atomicAdd(p, r0);
    atomicAdd(p + 1, r1);
  } else {
    outb[(size_t)i * 64 + lane] = (uint_t)f2bf(r0) | ((uint_t)f2bf(r1) << 16);
  }
}

__global__ __launch_bounds__(256) void k_cnt(const int* __restrict__ gidx, int* __restrict__ cnt, int n) {
  int i = blockIdx.x * 256 + threadIdx.x;
  if (i < n) atomicAdd(&cnt[gidx[i]], 1);
}

// ---------------- Head: mean -> FC(relu) -> dot(Wout) + bout ----------------
__global__ __launch_bounds__(128) void k_head(const float* __restrict__ pool, const int* __restrict__ cnt,
                                              const float* __restrict__ Wfc, const float* __restrict__ bfc,
                                              const float* __restrict__ Wout, const float* __restrict__ bout,
                                              float* __restrict__ out) {
  __shared__ float pv[128];
  __shared__ float red[128];
  int g = blockIdx.x, t = threadIdx.x;
  float c = fmaxf((float)cnt[g], 1.f);
  pv[t] = pool[(size_t)g * 128 + t] / c;
  __syncthreads();
  float acc = bfc[t];
#pragma unroll 8
  for (int k = 0; k < 128; k++) acc += pv[k] * Wfc[k * 128 + t];
  acc = fmaxf(acc, 0.f);
  red[t] = acc * Wout[t];
  __syncthreads();
  for (int o = 64; o > 0; o >>= 1) { if (t < o) red[t] += red[t + o]; __syncthreads(); }
  if (t == 0) out[g] = red[0] + bout[0];
}

// ---------------- launch ----------------

extern "C" void kernel_launch(void* const* d_in, const int* in_sizes, int n_in,
                              void* d_out, int out_size, void* d_ws, size_t ws_size,
                              hipStream_t stream) {
  const float* X    = (const float*)d_in[0];
  const int*   adj  = (const int*)d_in[1];
  const int*   gidx = (const int*)d_in[2];
  // d_in[3] = is_training (ignored; dropout rate is 0)
  const float* W1   = (const float*)d_in[4];
  const float* b1   = (const float*)d_in[5];
  const float* W2   = (const float*)d_in[6];
  const float* b2   = (const float*)d_in[7];
  const float* Wfc  = (const float*)d_in[8];
  const float* bfc  = (const float*)d_in[9];
  const float* Wout = (const float*)d_in[10];
  const float* bout = (const float*)d_in[11];
  (void)n_in; (void)ws_size;

  const int N = in_sizes[2];        // 100000
  const int E = in_sizes[1] / 2;    // 1600000
  const int G = out_size;           // 1024 (OUT=1)
  const int* srcv = adj;
  const int* dstv = adj + E;

  char* w = (char*)d_ws;
  size_t off = 0;
  auto alloc = [&](size_t bytes) -> void* {
    void* p = (void*)(w + off);
    off += (bytes + 255) & ~(size_t)255;
    return p;
  };
  uint_t*   bufA = (uint_t*)alloc((size_t)N * 64 * sizeof(uint_t));   // hn bf16-packed (gemm out), both layers
  uint_t*   bufB = (uint_t*)alloc((size_t)N * 64 * sizeof(uint_t));   // layer-1 activations (bf16-packed)
  float*    pool = (float*)alloc((size_t)G * 128 * sizeof(float));
  float*    nrm  = (float*)alloc((size_t)N * sizeof(float));
  int*      deg  = (int*)alloc((size_t)N * sizeof(int));
  int*      offs = (int*)alloc((size_t)N * sizeof(int));
  int*      fill = (int*)alloc((size_t)N * sizeof(int));
  int*      esrc = (int*)alloc((size_t)E * sizeof(int));
  int*      cnt  = (int*)alloc((size_t)G * sizeof(int));
  const int nb = (N + 1023) / 1024;   // 98 (<=256 required by k_scanB)
  int*      bsum  = (int*)alloc((size_t)nb * sizeof(int));
  int*      bbase = (int*)alloc((size_t)nb * sizeof(int));

  hipMemsetAsync(deg,  0, (size_t)N * sizeof(int), stream);
  hipMemsetAsync(fill, 0, (size_t)N * sizeof(int), stream);
  hipMemsetAsync(pool, 0, (size_t)G * 128 * sizeof(float), stream);
  hipMemsetAsync(cnt,  0, (size_t)G * sizeof(int), stream);

  // CSR build (dst-major)
  k_deg<<<(E + 255) / 256, 256, 0, stream>>>(dstv, deg, E);
  k_scanA<<<nb, 256, 0, stream>>>(deg, bsum, N);
  k_scanB<<<1, 256, 0, stream>>>(bsum, bbase, nb);
  k_scanC<<<nb, 256, 0, stream>>>(deg, bbase, offs, N);
  k_norm<<<(N + 255) / 256, 256, 0, stream>>>(deg, nrm, N);
  k_bucket<<<(E + 255) / 256, 256, 0, stream>>>(srcv, dstv, offs, fill, esrc, E);

  const int aggGrid = (N + 3) / 4;
  // layer 1
  k_gemm<false><<<(N + 31) / 32, 256, 0, stream>>>((const void*)X, W1, b1, nrm, bufA, N);
  k_agg<false><<<aggGrid, 256, 0, stream>>>(bufA, offs, deg, nrm, esrc, gidx, bufB, nullptr, N);
  // layer 2 (+ fused pooling)
  k_gemm<true><<<(N + 31) / 32, 256, 0, stream>>>((const void*)bufB, W2, b2, nrm, bufA, N);
  k_agg<true><<<aggGrid, 256, 0, stream>>>(bufA, offs, deg, nrm, esrc, gidx, nullptr, pool, N);
  k_cnt<<<(N + 255) / 256, 256, 0, stream>>>(gidx, cnt, N);
  // head
  k_head<<<G, 128, 0, stream>>>(pool, cnt, Wfc, bfc, Wout, bout, (float*)d_out);
}

// Round 4
// 586.860 us; speedup vs baseline: 1.3451x; 1.0543x over previous
//
#include <hip/hip_runtime.h>

// SparseGCNPredicator on MI355X — all float tensors are f32.
// R4: MFMA bf16 GEMM (128x128 tile, pre-transposed W fragments) replaces the
// f32 VALU GEMM; aggregation edge loop batches 8 gathers in flight.

typedef unsigned short ushort_t;
typedef unsigned int   uint_t;
typedef __attribute__((ext_vector_type(8))) short bf16x8;
typedef __attribute__((ext_vector_type(4))) float f32x4;

__device__ __forceinline__ float bf2f(uint_t u) { return __uint_as_float(u << 16); }
__device__ __forceinline__ ushort_t f2bf(float f) {
  uint_t x = __float_as_uint(f);
  x = x + 0x7fffu + ((x >> 16) & 1u);   // round-to-nearest-even
  return (ushort_t)(x >> 16);
}

// ---------------- CSR build ----------------

__global__ __launch_bounds__(256) void k_deg(const int* __restrict__ dst, int* __restrict__ deg, int E) {
  int e = blockIdx.x * 256 + threadIdx.x;
  if (e < E) atomicAdd(&deg[dst[e]], 1);
}

__global__ __launch_bounds__(256) void k_scanA(const int* __restrict__ deg, int* __restrict__ bsum, int n) {
  __shared__ int s[256];
  int t = threadIdx.x;
  int base = blockIdx.x * 1024 + t * 4;
  int sum = 0;
#pragma unroll
  for (int j = 0; j < 4; j++) { int i = base + j; if (i < n) sum += deg[i]; }
  s[t] = sum; __syncthreads();
  for (int off = 128; off > 0; off >>= 1) { if (t < off) s[t] += s[t + off]; __syncthreads(); }
  if (t == 0) bsum[blockIdx.x] = s[0];
}

__global__ __launch_bounds__(256) void k_scanB(const int* __restrict__ bsum, int* __restrict__ bbase, int nb) {
  __shared__ int s[256];
  int t = threadIdx.x;
  s[t] = (t < nb) ? bsum[t] : 0;
  __syncthreads();
  for (int off = 1; off < 256; off <<= 1) {
    int a = s[t];
    int add = (t >= off) ? s[t - off] : 0;
    __syncthreads();
    s[t] = a + add;
    __syncthreads();
  }
  if (t < nb) bbase[t] = (t > 0) ? s[t - 1] : 0;
}

__global__ __launch_bounds__(256) void k_scanC(const int* __restrict__ deg, const int* __restrict__ bbase,
                                               int* __restrict__ offs, int n) {
  __shared__ int s[256];
  int t = threadIdx.x;
  int base = blockIdx.x * 1024 + t * 4;
  int v[4]; int sum = 0;
#pragma unroll
  for (int j = 0; j < 4; j++) { int i = base + j; v[j] = (i < n) ? deg[i] : 0; sum += v[j]; }
  s[t] = sum; __syncthreads();
  for (int off = 1; off < 256; off <<= 1) {
    int a = s[t];
    int add = (t >= off) ? s[t - off] : 0;
    __syncthreads();
    s[t] = a + add;
    __syncthreads();
  }
  int excl = bbase[blockIdx.x] + ((t > 0) ? s[t - 1] : 0);
#pragma unroll
  for (int j = 0; j < 4; j++) { int i = base + j; if (i < n) offs[i] = excl; excl += v[j]; }
}

__global__ __launch_bounds__(256) void k_norm(const int* __restrict__ deg, float* __restrict__ nrm, int n) {
  int i = blockIdx.x * 256 + threadIdx.x;
  if (i < n) {
    int d = deg[i];
    nrm[i] = (d > 0) ? rsqrtf((float)d) : 0.f;
  }
}

__global__ __launch_bounds__(256) void k_bucket(const int* __restrict__ src, const int* __restrict__ dst,
                                                const int* __restrict__ offs, int* __restrict__ fill,
                                                int* __restrict__ esrc, int E) {
  int e = blockIdx.x * 256 + threadIdx.x;
  if (e >= E) return;
  int d = dst[e];
  int p = offs[d] + atomicAdd(&fill[d], 1);
  esrc[p] = src[e];
}

// ---------------- W pre-transform: Wf[(q*128 + n)*8 + j] = bf16(W[q*8+j][n]) ----------------
// Fragment-friendly layout: lane n reads its 8 consecutive k's as one b128.
__global__ __launch_bounds__(256) void k_prepW(const float* __restrict__ W, ushort_t* __restrict__ Wf) {
  int idx = blockIdx.x * 256 + threadIdx.x;   // 0..16383
  int n = idx & 127, k = idx >> 7;
  float v = W[(size_t)k * 128 + n];
  Wf[((size_t)(k >> 3) * 128 + n) * 8 + (k & 7)] = f2bf(v);
}

// ---------------- MFMA GEMM: Yb[r] = bf16( (X[r] @ W + b) * norm[r] ) ----------------
// 128 rows x 128 cols per 256-thread block (4 waves). Wave w: rows w*32..w*32+31
// (2 m-tiles of 16), all 8 col-tiles. K=128 in 4 chunks of 32.
// LDS: Xs/Ws in [q][idx] chunk layout (q = k>>3), 32 KB each = 64 KB total.
template <bool BF16IN>
__global__ __launch_bounds__(256) void k_gemm_mfma(const void* __restrict__ Xv, const ushort_t* __restrict__ Wf,
                                                   const float* __restrict__ bias, const float* __restrict__ nrm,
                                                   ushort_t* __restrict__ Yb, int nrows) {
  __shared__ ushort_t Xs[16384];   // [(q*128 + m)*8 + j]
  __shared__ ushort_t Ws[16384];   // [(q*128 + n)*8 + j]
  int tid = threadIdx.x;
  int r0 = blockIdx.x * 128;
  // stage W fragments: straight 32 KB copy
  {
    const uint4* s = (const uint4*)Wf;
    uint4* d = (uint4*)Ws;
#pragma unroll
    for (int i = 0; i < 8; i++) d[tid + 256 * i] = s[tid + 256 * i];
  }
  // stage X tile into chunk layout
  if (BF16IN) {
    const uint4* Xp = (const uint4*)Xv;        // row = 16 uint4 (one chunk each)
    uint4* Xs4 = (uint4*)Xs;
#pragma unroll
    for (int i = 0; i < 8; i++) {
      int idx = tid + 256 * i;                 // 0..2047
      int m = idx >> 4, q = idx & 15;
      int gm = r0 + m;
      uint4 v = make_uint4(0u, 0u, 0u, 0u);
      if (gm < nrows) v = Xp[(size_t)gm * 16 + q];
      Xs4[q * 128 + m] = v;
    }
  } else {
    const float4* Xp = (const float4*)Xv;      // row = 32 float4
#pragma unroll
    for (int i = 0; i < 16; i++) {
      int idx = tid + 256 * i;                 // 0..4095
      int m = idx >> 5, k4 = idx & 31;
      int gm = r0 + m;
      float4 v = make_float4(0.f, 0.f, 0.f, 0.f);
      if (gm < nrows) v = Xp[(size_t)gm * 32 + k4];
      uint2 p;
      p.x = (uint_t)f2bf(v.x) | ((uint_t)f2bf(v.y) << 16);
      p.y = (uint_t)f2bf(v.z) | ((uint_t)f2bf(v.w) << 16);
      *((uint2*)(Xs + ((size_t)(k4 >> 1) * 128 + m) * 8 + (size_t)(k4 & 1) * 4)) = p;
    }
  }
  __syncthreads();

  int wave = tid >> 6, lane = tid & 63;
  int ln = lane & 15, quad = lane >> 4;
  const bf16x8* Xf = (const bf16x8*)Xs;
  const bf16x8* Wb = (const bf16x8*)Ws;
  f32x4 acc[2][8];
#pragma unroll
  for (int mt = 0; mt < 2; mt++)
#pragma unroll
    for (int ct = 0; ct < 8; ct++) acc[mt][ct] = (f32x4){0.f, 0.f, 0.f, 0.f};

#pragma unroll
  for (int kc = 0; kc < 4; kc++) {
    int q = kc * 4 + quad;
    bf16x8 a0 = Xf[q * 128 + wave * 32 + ln];
    bf16x8 a1 = Xf[q * 128 + wave * 32 + 16 + ln];
#pragma unroll
    for (int ct = 0; ct < 8; ct++) {
      bf16x8 b = Wb[q * 128 + ct * 16 + ln];
      acc[0][ct] = __builtin_amdgcn_mfma_f32_16x16x32_bf16(a0, b, acc[0][ct], 0, 0, 0);
      acc[1][ct] = __builtin_amdgcn_mfma_f32_16x16x32_bf16(a1, b, acc[1][ct], 0, 0, 0);
    }
  }

  // epilogue: D row = base_m + quad*4 + reg, col = ct*16 + ln
#pragma unroll
  for (int mt = 0; mt < 2; mt++) {
    int rbase = r0 + wave * 32 + mt * 16 + quad * 4;
    float nv[4];
#pragma unroll
    for (int reg = 0; reg < 4; reg++) {
      int r = rbase + reg;
      nv[reg] = (r < nrows) ? nrm[r] : 0.f;
    }
#pragma unroll
    for (int ct = 0; ct < 8; ct++) {
      int col = ct * 16 + ln;
      float bcol = bias[col];
#pragma unroll
      for (int reg = 0; reg < 4; reg++) {
        int r = rbase + reg;
        if (r < nrows) {
          float val = (acc[mt][ct][reg] + bcol) * nv[reg];
          Yb[(size_t)r * 128 + col] = f2bf(val);
        }
      }
    }
  }
}

// ---------------- Aggregation: relu(norm[i] * sum_{e in CSR[i]} hn_bf16[src_e]) ----------------
// One wave per node; lane owns channels {2l,2l+1} (one uint). 8 gathers
// batched in flight before accumulation (4 chains).
template <bool POOL>
__global__ __launch_bounds__(256) void k_agg(const uint_t* __restrict__ hn, const int* __restrict__ offs,
                                             const int* __restrict__ deg, const float* __restrict__ nrm,
                                             const int* __restrict__ esrc, const int* __restrict__ gidx,
                                             uint_t* __restrict__ outb, float* __restrict__ pool, int N) {
  int wave = threadIdx.x >> 6;
  int lane = threadIdx.x & 63;
  int i = blockIdx.x * 4 + wave;
  if (i >= N) return;
  int o = offs[i], d = deg[i];
  const uint_t* base = hn + lane;
  float s0 = 0.f, s1 = 0.f, t0 = 0.f, t1 = 0.f;
  float u0 = 0.f, u1 = 0.f, v0 = 0.f, v1 = 0.f;
  int e = o, end = o + d;
  for (; e + 8 <= end; e += 8) {
    int ix[8];
#pragma unroll
    for (int j = 0; j < 8; j++) ix[j] = esrc[e + j];
    uint_t g[8];
#pragma unroll
    for (int j = 0; j < 8; j++) g[j] = base[(size_t)ix[j] * 64];
    s0 += bf2f(g[0] & 0xffffu) + bf2f(g[4] & 0xffffu);
    s1 += bf2f(g[0] >> 16)     + bf2f(g[4] >> 16);
    t0 += bf2f(g[1] & 0xffffu) + bf2f(g[5] & 0xffffu);
    t1 += bf2f(g[1] >> 16)     + bf2f(g[5] >> 16);
    u0 += bf2f(g[2] & 0xffffu) + bf2f(g[6] & 0xffffu);
    u1 += bf2f(g[2] >> 16)     + bf2f(g[6] >> 16);
    v0 += bf2f(g[3] & 0xffffu) + bf2f(g[7] & 0xffffu);
    v1 += bf2f(g[3] >> 16)     + bf2f(g[7] >> 16);
  }
  for (; e < end; e++) {
    uint_t a = base[(size_t)esrc[e] * 64];
    s0 += bf2f(a & 0xffffu); s1 += bf2f(a >> 16);
  }
  float nv = nrm[i];
  float r0 = fmaxf((s0 + t0 + u0 + v0) * nv, 0.f);
  float r1 = fmaxf((s1 + t1 + u1 + v1) * nv, 0.f);
  if (POOL) {
    float* p = pool + (size_t)gidx[i] * 128 + 2 * lane;
    atomicAdd(p, r0);
    atomicAdd(p + 1, r1);
  } else {
    outb[(size_t)i * 64 + lane] = (uint_t)f2bf(r0) | ((uint_t)f2bf(r1) << 16);
  }
}

__global__ __launch_bounds__(256) void k_cnt(const int* __restrict__ gidx, int* __restrict__ cnt, int n) {
  int i = blockIdx.x * 256 + threadIdx.x;
  if (i < n) atomicAdd(&cnt[gidx[i]], 1);
}

// ---------------- Head: mean -> FC(relu) -> dot(Wout) + bout ----------------
__global__ __launch_bounds__(128) void k_head(const float* __restrict__ pool, const int* __restrict__ cnt,
                                              const float* __restrict__ Wfc, const float* __restrict__ bfc,
                                              const float* __restrict__ Wout, const float* __restrict__ bout,
                                              float* __restrict__ out) {
  __shared__ float pv[128];
  __shared__ float red[128];
  int g = blockIdx.x, t = threadIdx.x;
  float c = fmaxf((float)cnt[g], 1.f);
  pv[t] = pool[(size_t)g * 128 + t] / c;
  __syncthreads();
  float acc = bfc[t];
#pragma unroll 8
  for (int k = 0; k < 128; k++) acc += pv[k] * Wfc[k * 128 + t];
  acc = fmaxf(acc, 0.f);
  red[t] = acc * Wout[t];
  __syncthreads();
  for (int o = 64; o > 0; o >>= 1) { if (t < o) red[t] += red[t + o]; __syncthreads(); }
  if (t == 0) out[g] = red[0] + bout[0];
}

// ---------------- launch ----------------

extern "C" void kernel_launch(void* const* d_in, const int* in_sizes, int n_in,
                              void* d_out, int out_size, void* d_ws, size_t ws_size,
                              hipStream_t stream) {
  const float* X    = (const float*)d_in[0];
  const int*   adj  = (const int*)d_in[1];
  const int*   gidx = (const int*)d_in[2];
  // d_in[3] = is_training (ignored; dropout rate is 0)
  const float* W1   = (const float*)d_in[4];
  const float* b1   = (const float*)d_in[5];
  const float* W2   = (const float*)d_in[6];
  const float* b2   = (const float*)d_in[7];
  const float* Wfc  = (const float*)d_in[8];
  const float* bfc  = (const float*)d_in[9];
  const float* Wout = (const float*)d_in[10];
  const float* bout = (const float*)d_in[11];
  (void)n_in; (void)ws_size;

  const int N = in_sizes[2];        // 100000
  const int E = in_sizes[1] / 2;    // 1600000
  const int G = out_size;           // 1024 (OUT=1)
  const int* srcv = adj;
  const int* dstv = adj + E;

  char* w = (char*)d_ws;
  size_t off = 0;
  auto alloc = [&](size_t bytes) -> void* {
    void* p = (void*)(w + off);
    off += (bytes + 255) & ~(size_t)255;
    return p;
  };
  ushort_t* bufA = (ushort_t*)alloc((size_t)N * 128 * sizeof(ushort_t)); // hn bf16 (gemm out), both layers
  ushort_t* bufB = (ushort_t*)alloc((size_t)N * 128 * sizeof(ushort_t)); // layer-1 activations (bf16)
  float*    pool = (float*)alloc((size_t)G * 128 * sizeof(float));
  float*    nrm  = (float*)alloc((size_t)N * sizeof(float));
  int*      deg  = (int*)alloc((size_t)N * sizeof(int));
  int*      offs = (int*)alloc((size_t)N * sizeof(int));
  int*      fill = (int*)alloc((size_t)N * sizeof(int));
  int*      esrc = (int*)alloc((size_t)E * sizeof(int));
  int*      cnt  = (int*)alloc((size_t)G * sizeof(int));
  ushort_t* Wf1  = (ushort_t*)alloc((size_t)128 * 128 * sizeof(ushort_t));
  ushort_t* Wf2  = (ushort_t*)alloc((size_t)128 * 128 * sizeof(ushort_t));
  const int nb = (N + 1023) / 1024;   // 98 (<=256 required by k_scanB)
  int*      bsum  = (int*)alloc((size_t)nb * sizeof(int));
  int*      bbase = (int*)alloc((size_t)nb * sizeof(int));

  hipMemsetAsync(deg,  0, (size_t)N * sizeof(int), stream);
  hipMemsetAsync(fill, 0, (size_t)N * sizeof(int), stream);
  hipMemsetAsync(pool, 0, (size_t)G * 128 * sizeof(float), stream);
  hipMemsetAsync(cnt,  0, (size_t)G * sizeof(int), stream);

  // W fragment pre-transform (independent of CSR)
  k_prepW<<<64, 256, 0, stream>>>(W1, Wf1);
  k_prepW<<<64, 256, 0, stream>>>(W2, Wf2);

  // CSR build (dst-major)
  k_deg<<<(E + 255) / 256, 256, 0, stream>>>(dstv, deg, E);
  k_scanA<<<nb, 256, 0, stream>>>(deg, bsum, N);
  k_scanB<<<1, 256, 0, stream>>>(bsum, bbase, nb);
  k_scanC<<<nb, 256, 0, stream>>>(deg, bbase, offs, N);
  k_norm<<<(N + 255) / 256, 256, 0, stream>>>(deg, nrm, N);
  k_bucket<<<(E + 255) / 256, 256, 0, stream>>>(srcv, dstv, offs, fill, esrc, E);

  const int aggGrid = (N + 3) / 4;
  const int gemmGrid = (N + 127) / 128;
  // layer 1
  k_gemm_mfma<false><<<gemmGrid, 256, 0, stream>>>((const void*)X, Wf1, b1, nrm, bufA, N);
  k_agg<false><<<aggGrid, 256, 0, stream>>>((const uint_t*)bufA, offs, deg, nrm, esrc, gidx, (uint_t*)bufB, nullptr, N);
  // layer 2 (+ fused pooling)
  k_gemm_mfma<true><<<gemmGrid, 256, 0, stream>>>((const void*)bufB, Wf2, b2, nrm, bufA, N);
  k_agg<true><<<aggGrid, 256, 0, stream>>>((const uint_t*)bufA, offs, deg, nrm, esrc, gidx, nullptr, pool, N);
  k_cnt<<<(N + 255) / 256, 256, 0, stream>>>(gidx, cnt, N);
  // head
  k_head<<<G, 128, 0, stream>>>(pool, cnt, Wfc, bfc, Wout, bout, (float*)d_out);
}